// Round 9
// baseline (160.472 us; speedup 1.0000x reference)
//
#include <hip/hip_runtime.h>
#include <hip/hip_bf16.h>

#define NB 2
#define SEQ 2048
#define DM 384
#define NH 8
#define HD 48
#define QKVN 1152

typedef __hip_bfloat16 bf16;
typedef __attribute__((ext_vector_type(8))) short short8;
typedef __attribute__((ext_vector_type(4))) float float4v;
typedef __attribute__((ext_vector_type(16))) float f32x16;

static __device__ __forceinline__ float bf2f(bf16 v){ return __bfloat162float(v); }
static __device__ __forceinline__ float ldin(const void* p, size_t i, int isf){
    return isf ? ((const float*)p)[i] : bf2f(((const bf16*)p)[i]);
}
// fp32 -> bf16 bits, RNE
static __device__ __forceinline__ short f2b(float f){
    union { float f; unsigned u; } a; a.f = f;
    unsigned r = a.u + 0x7FFFu + ((a.u >> 16) & 1u);
    return (short)(r >> 16);
}
// packed fp32x2 -> bf16x2 (v_cvt_pk_bf16_f32)
static __device__ __forceinline__ unsigned pk2(float a, float b){
    union { __hip_bfloat162 h; unsigned u; } r;
    r.h = __float22bfloat162_rn(float2{a, b});
    return r.u;
}
static __device__ __forceinline__ float bflo(unsigned u){
    union { unsigned u; float f; } a; a.u = u << 16; return a.f;
}
static __device__ __forceinline__ float bfhi(unsigned u){
    union { unsigned u; float f; } a; a.u = u & 0xFFFF0000u; return a.f;
}
static __device__ __forceinline__ short8 u4pack(unsigned w0, unsigned w1, unsigned w2, unsigned w3){
    union { unsigned u[4]; short8 s; } r; r.u[0]=w0; r.u[1]=w1; r.u[2]=w2; r.u[3]=w3; return r.s;
}
// per-block input dtype probe (0 = bf16, 1 = fp32); wave-uniform
static __device__ __forceinline__ int detect_isf(const void* x){
    const unsigned short* xb = (const unsigned short*)x;
    int l = threadIdx.x & 63;
    union { unsigned u; float f; } a; a.u = ((unsigned)xb[2*l]) << 16;
    float ab = fabsf(a.f);
    int good = (a.f == 0.0f) || (ab > 9.765625e-4f && ab < 1024.0f);
    unsigned long long m = __ballot(good);
    return (__popcll(m) >= 32) ? 0 : 1;
}

// ---------------- K1: WqT transpose only (biases are inlined at point of use now;
// WoT moved into k_qkv_dist tail blocks — consumed two kernels later).
__global__ __launch_bounds__(256) void k_wt(const void* __restrict__ x,
    const void* __restrict__ Wqkv, short* __restrict__ WqT)
{
    const int isf = detect_isf(x);
    const int t = threadIdx.x;
    const int b = blockIdx.x;          // 0..431
    const int kt = b / 36, nt = b % 36;
    const int k0 = kt*32, n0 = nt*32;
    __shared__ float Ls[32][33];
    for (int idx = t; idx < 1024; idx += 256) {
        int r = idx >> 5, c = idx & 31;
        Ls[r][c] = ldin(Wqkv, (size_t)(k0+r)*QKVN + n0 + c, isf);
    }
    __syncthreads();
    for (int idx = t; idx < 1024; idx += 256) {
        int r2 = idx >> 5, c2 = idx & 31;
        WqT[(size_t)(n0+r2)*DM + k0 + c2] = f2b(Ls[c2][r2]);
    }
}

// ---------------- K2: fused {qkv GEMM [0,576) | dist8 [576,1088) | WoT [1088,1232)}.
// GEMM k-loop is register-prefetch pipelined (T14 issue-early/write-late): LOAD(k+1)
// into regs right after the LDS-write barrier so its ~900cy cold-HBM flight hides under
// tile k's MFMA. R8 counters showed per-block serial latency is the binding term
// (Occ 21%, VALU 18%, MFMA 2.8%, HBM 16% — nothing saturated).
// qg3/kg3: [bh][t32(64)][dc(3)][hi(2)][tok(32)][e(8)]  elem = X[tok][dc*16 + hi*8 + e]
// vg3:     [bh][jt(64)][jc(2)]{ dt0:[hi][32 d][e8] , dt1:[hi][16 d][e8] } 1536 s/tile.
//          slot (hi,e) holds token j = jc*16 + (e&3) + 8*(e>>2) + 4*hi (verified 32x32
//          C-row order) so PV's A-operand is the raw sacc register order — no cross-lane.
// dist8: [b][jg = j>>2 (512)][i(2048)][jj(4)] bf16 (R6 mapping — best measured).
__global__ __launch_bounds__(256) void k_qkv_dist(const void* __restrict__ x,
    const void* __restrict__ coords,
    const short* __restrict__ WT, const void* __restrict__ bqkv,
    const void* __restrict__ Wout,
    short* __restrict__ qg3, short* __restrict__ kg3, short* __restrict__ vg3,
    short* __restrict__ dist8, short* __restrict__ WoT)
{
    __shared__ __align__(16) short As[64*72];
    __shared__ __align__(16) short Bs[128*72];   // reused as epilogue buffer
    __shared__ float cjx[16], cjy[16], cjz[16];
    const int isf = detect_isf(x);
    const int t = threadIdx.x;
    const int bid = blockIdx.x;
    if (bid >= 1088) {
        // ---- WoT transpose section (consumed by k_out, two kernels later)
        const int b = bid - 1088;        // 0..143
        const int kt = b / 12, nt = b % 12;
        const int k0 = kt*32, n0 = nt*32;
        float (*Ls)[33] = (float(*)[33])As;   // alias: this path doesn't use As/Bs
        for (int idx = t; idx < 1024; idx += 256) {
            int r = idx >> 5, c = idx & 31;
            Ls[r][c] = ldin(Wout, (size_t)(k0+r)*DM + n0 + c, isf);
        }
        __syncthreads();
        for (int idx = t; idx < 1024; idx += 256) {
            int r2 = idx >> 5, c2 = idx & 31;
            WoT[(size_t)(n0+r2)*DM + k0 + c2] = f2b(Ls[c2][r2]);
        }
        return;
    }
    if (bid >= 576) {
        // ---- dist section (R6 mapping)
        const int b = bid - 576;             // 0..511
        const int bb = b >> 8;               // batch
        const int jg = (b >> 1) & 127;       // 16-j group
        const int j0 = jg * 16;
        const int ih = (b & 1) * 1024;       // i-half
        if (t < 16) {
            int gj = (bb*SEQ + j0 + t)*3;
            cjx[t] = ldin(coords, gj, isf);
            cjy[t] = ldin(coords, gj+1, isf);
            cjz[t] = ldin(coords, gj+2, isf);
        }
        __syncthreads();
        #pragma unroll
        for (int k = 0; k < 4; ++k) {
            int i = ih + k*256 + t;
            int gi = (bb*SEQ + i)*3;
            float px = ldin(coords, gi, isf), py = ldin(coords, gi+1, isf), pz = ldin(coords, gi+2, isf);
            short o[16];
            #pragma unroll
            for (int e = 0; e < 16; ++e) {
                float dx = px - cjx[e], dy = py - cjy[e], dz = pz - cjz[e];
                o[e] = f2b(sqrtf(dx*dx + dy*dy + dz*dz));
            }
            short* dst = dist8 + (((size_t)bb*512 + (size_t)jg*4)*SEQ + i)*4;
            *(int2*)(dst)          = *(const int2*)(o);
            *(int2*)(dst + SEQ*4)  = *(const int2*)(o + 4);
            *(int2*)(dst + SEQ*8)  = *(const int2*)(o + 8);
            *(int2*)(dst + SEQ*12) = *(const int2*)(o + 12);
        }
        return;
    }
    // ---- qkv GEMM section, pipelined
    const int w = t >> 6, lane = t & 63, L = lane & 15, quad = lane >> 4;
    const int mt = bid / 9, nt = bid % 9;
    const int row0 = mt*64, col0 = nt*128;
    const int wm = w & 1, wn = w >> 1;
    float4v acc[2][4] = {};
    int4 rA[4], rB[4];
    // LOAD tile 0
    {
        const int k0 = 0;
        #pragma unroll
        for (int ci = 0; ci < 2; ++ci) {
            int c = t + ci*256; int row = c >> 3, k8 = c & 7;
            size_t src = (size_t)(row0+row)*DM + k0 + k8*8;
            if (isf) {
                rA[2*ci]   = *(const int4*)((const float*)x + src);
                rA[2*ci+1] = *(const int4*)((const float*)x + src + 4);
            } else {
                rA[ci] = *(const int4*)((const short*)x + src);
            }
        }
        #pragma unroll
        for (int ci = 0; ci < 4; ++ci) {
            int c = t + ci*256; int row = c >> 3, k8 = c & 7;
            rB[ci] = *(const int4*)(WT + (size_t)(col0+row)*DM + k0 + k8*8);
        }
    }
    for (int ks = 0; ks < 6; ++ks) {
        __syncthreads();
        // WRITE regs -> LDS
        #pragma unroll
        for (int ci = 0; ci < 2; ++ci) {
            int c = t + ci*256; int row = c >> 3, k8 = c & 7;
            if (isf) {
                union { int4 i[2]; float f[8]; } u; u.i[0] = rA[2*ci]; u.i[1] = rA[2*ci+1];
                short o[8];
                #pragma unroll
                for (int e = 0; e < 8; ++e) o[e] = f2b(u.f[e]);
                *(int4*)(&As[row*72 + k8*8]) = *(const int4*)o;
            } else {
                *(int4*)(&As[row*72 + k8*8]) = rA[ci];
            }
        }
        #pragma unroll
        for (int ci = 0; ci < 4; ++ci) {
            int c = t + ci*256; int row = c >> 3, k8 = c & 7;
            *(int4*)(&Bs[row*72 + k8*8]) = rB[ci];
        }
        __syncthreads();
        // ISSUE next tile's loads (fly under this tile's MFMA)
        if (ks < 5) {
            const int k0 = (ks+1)*64;
            #pragma unroll
            for (int ci = 0; ci < 2; ++ci) {
                int c = t + ci*256; int row = c >> 3, k8 = c & 7;
                size_t src = (size_t)(row0+row)*DM + k0 + k8*8;
                if (isf) {
                    rA[2*ci]   = *(const int4*)((const float*)x + src);
                    rA[2*ci+1] = *(const int4*)((const float*)x + src + 4);
                } else {
                    rA[ci] = *(const int4*)((const short*)x + src);
                }
            }
            #pragma unroll
            for (int ci = 0; ci < 4; ++ci) {
                int c = t + ci*256; int row = c >> 3, k8 = c & 7;
                rB[ci] = *(const int4*)(WT + (size_t)(col0+row)*DM + k0 + k8*8);
            }
        }
        // MFMA on LDS tile ks
        #pragma unroll
        for (int kc = 0; kc < 2; ++kc) {
            short8 a0 = *(const short8*)(&As[(32*wm + L)*72 + kc*32 + quad*8]);
            short8 a1 = *(const short8*)(&As[(32*wm + 16 + L)*72 + kc*32 + quad*8]);
            #pragma unroll
            for (int ni = 0; ni < 4; ++ni) {
                short8 bf = *(const short8*)(&Bs[(64*wn + 16*ni + L)*72 + kc*32 + quad*8]);
                acc[0][ni] = __builtin_amdgcn_mfma_f32_16x16x32_bf16(a0, bf, acc[0][ni], 0, 0, 0);
                acc[1][ni] = __builtin_amdgcn_mfma_f32_16x16x32_bf16(a1, bf, acc[1][ni], 0, 0, 0);
            }
        }
    }
    const int which = col0 / DM;     // uniform per block (0=q,1=k,2=v)
    const int cbase = col0 % DM;
    short* Ep = Bs;
    __syncthreads();
    if (which < 2) {
        // row-major Ep[64 tokens][136]
        #pragma unroll
        for (int mi = 0; mi < 2; ++mi)
            #pragma unroll
            for (int ni = 0; ni < 4; ++ni) {
                int col_l = 64*wn + 16*ni + L;
                float bv = ldin(bqkv, col0 + col_l, isf);
                #pragma unroll
                for (int r = 0; r < 4; ++r) {
                    int row_l = 32*wm + 16*mi + quad*4 + r;
                    Ep[row_l*136 + col_l] = f2b(acc[mi][ni][r] + bv);
                }
            }
        __syncthreads();
        short* dst = which ? kg3 : qg3;
        for (int c = t; c < 1024; c += 256) {
            int row_l = c >> 4, col_l = (c & 15)*8;   // 8 consecutive d, one token
            int row_g = row0 + row_l;
            int bi = row_g >> 11, nn = row_g & (SEQ-1);
            int c2 = cbase + col_l;
            int hh = c2/HD, dh = c2%HD;
            int bh = bi*NH + hh;
            int dc = dh >> 4, hi = (dh >> 3) & 1;
            size_t dstoff = ((size_t)bh*64 + (nn>>5))*1536 + (size_t)((dc*2 + hi)*256 + (nn&31)*8);
            *(int4*)(dst + dstoff) = *(const int4*)(&Ep[row_l*136 + col_l]);
        }
    } else {
        // col-major Ep[128 cols][72 tokens]
        #pragma unroll
        for (int mi = 0; mi < 2; ++mi)
            #pragma unroll
            for (int ni = 0; ni < 4; ++ni) {
                int col_l = 64*wn + 16*ni + L;
                float bv = ldin(bqkv, col0 + col_l, isf);
                #pragma unroll
                for (int r = 0; r < 4; ++r) {
                    int row_l = 32*wm + 16*mi + quad*4 + r;
                    Ep[col_l*72 + row_l] = f2b(acc[mi][ni][r] + bv);
                }
            }
        __syncthreads();
        for (int c = t; c < 1024; c += 256) {
            int col_l = c >> 3, row8 = (c & 7)*8;     // 8 consecutive tokens, one d
            int row_g = row0 + row8;
            int bi = row_g >> 11, nn = row_g & (SEQ-1);
            int c2 = cbase + col_l;
            int hh = c2/HD, dh = c2%HD;
            int bh = bi*NH + hh;
            int jt = nn >> 5, jc = (nn >> 4) & 1;
            int ehalf = ((nn >> 3) & 1)*4;            // e>>2 half of the slot
            int dt = dh >> 5, dp = dh & 31;           // d-tile 0: 32 cols, d-tile 1: 16 cols
            int hstride = dt ? 128 : 256;
            size_t base = ((size_t)bh*64 + jt)*1536 + (size_t)(jc*768 + dt*512 + dp*8 + ehalf);
            *(int2*)(vg3 + base)           = *(const int2*)(&Ep[col_l*72 + row8]);
            *(int2*)(vg3 + base + hstride) = *(const int2*)(&Ep[col_l*72 + row8 + 4]);
        }
    }
}

// ---------------- K3: flash attention on 32x32x16 MFMA, 32 i per block, grid 1024
// 4/CU = 16 waves/CU. 4 waves split the j-range (wave w: tiles 4s+w). QK^T: 3 pad-free
// K=16 MFMA; sacc: i = lane&31, slot r -> j = jb + (r&3) + 8*(r>>2) + 4*hi (m74/m101).
// PV: pa in raw sacc register order (V slot-permuted at prep). setprio around MFMA
// clusters (independent waves — m191 regime). wd/bd computed inline from Wdist/bdist.
// Swizzle: XCD x hosts all 8 heads of one (batch, 16-it band).
__global__ __launch_bounds__(256, 4) void k_attn(
    const short* __restrict__ qg3, const short* __restrict__ kg3, const short* __restrict__ vg3,
    const short* __restrict__ dist8, const void* __restrict__ Wdist,
    const void* __restrict__ bdist, short* __restrict__ aob, const void* __restrict__ x)
{
    __shared__ float Ored[2][32*48];
    __shared__ float Lred[2][32];
    const int isf = detect_isf(x);
    const int t = threadIdx.x;
    const int w = t >> 6, lane = t & 63;
    const int li = lane & 31, hi = lane >> 5;
    const int xcd  = blockIdx.x & 7;
    const int slot = blockIdx.x >> 3;        // 0..127
    const int bi   = xcd >> 2;               // batch
    const int band = xcd & 3;                // 16-it band
    const int hh   = slot & 7;
    const int it   = band*16 + (slot >> 3);  // 0..63
    const int bh   = bi*NH + hh;
    const int i0 = it*32;
    const float log2e = 1.4426950408889634f;
    const float scale2 = 0.14433756729740643f * log2e;
    const float wd = ldin(Wdist, hh, isf) * log2e;
    const float bd = ldin(bdist, hh, isf) * log2e;

    const short* qB = qg3 + ((size_t)bh*64 + it)*1536 + hi*256 + li*8;
    const short8 qf0 = *(const short8*)(qB);
    const short8 qf1 = *(const short8*)(qB + 512);
    const short8 qf2 = *(const short8*)(qB + 1024);

    f32x16 accO0 = {}, accO1 = {};
    float rsum = 0.0f;

    const short* kBp = kg3 + ((size_t)bh*64 + w)*1536 + hi*256 + li*8;
    const short* vBp = vg3 + ((size_t)bh*64 + w)*1536 + li*8;
    const short* dBp = dist8 + (((size_t)bi*512 + (size_t)w*8 + hi)*SEQ + i0 + li)*4;

    for (int s = 0; s < 16; ++s) {
        short8 kf0 = *(const short8*)(kBp);
        short8 kf1 = *(const short8*)(kBp + 512);
        short8 kf2 = *(const short8*)(kBp + 1024);
        int2 du0 = *(const int2*)(dBp);
        int2 du1 = *(const int2*)(dBp + SEQ*8);
        int2 du2 = *(const int2*)(dBp + SEQ*16);
        int2 du3 = *(const int2*)(dBp + SEQ*24);
        f32x16 sacc = {};
        __builtin_amdgcn_s_setprio(1);
        sacc = __builtin_amdgcn_mfma_f32_32x32x16_bf16(kf0, qf0, sacc, 0, 0, 0);
        sacc = __builtin_amdgcn_mfma_f32_32x32x16_bf16(kf1, qf1, sacc, 0, 0, 0);
        sacc = __builtin_amdgcn_mfma_f32_32x32x16_bf16(kf2, qf2, sacc, 0, 0, 0);
        __builtin_amdgcn_s_setprio(0);
        float p[16];
        #pragma unroll
        for (int rq = 0; rq < 4; ++rq) {
            int2 du = rq == 0 ? du0 : rq == 1 ? du1 : rq == 2 ? du2 : du3;
            float d0 = bflo((unsigned)du.x), d1 = bfhi((unsigned)du.x);
            float d2 = bflo((unsigned)du.y), d3 = bfhi((unsigned)du.y);
            p[4*rq+0] = __builtin_amdgcn_exp2f(fmaf(sacc[4*rq+0], scale2, fmaf(d0, wd, bd)));
            p[4*rq+1] = __builtin_amdgcn_exp2f(fmaf(sacc[4*rq+1], scale2, fmaf(d1, wd, bd)));
            p[4*rq+2] = __builtin_amdgcn_exp2f(fmaf(sacc[4*rq+2], scale2, fmaf(d2, wd, bd)));
            p[4*rq+3] = __builtin_amdgcn_exp2f(fmaf(sacc[4*rq+3], scale2, fmaf(d3, wd, bd)));
            rsum += (p[4*rq+0] + p[4*rq+1]) + (p[4*rq+2] + p[4*rq+3]);
        }
        short8 pa0 = u4pack(pk2(p[0],p[1]),  pk2(p[2],p[3]),  pk2(p[4],p[5]),   pk2(p[6],p[7]));
        short8 pa1 = u4pack(pk2(p[8],p[9]),  pk2(p[10],p[11]),pk2(p[12],p[13]), pk2(p[14],p[15]));
        short8 v00 = *(const short8*)(vBp + hi*256);            // jc0, d 0..31
        short8 v10 = *(const short8*)(vBp + 768 + hi*256);      // jc1, d 0..31
        short8 v01 = *(const short8*)(vBp + 512 + hi*128);      // jc0, d 32..47 (cols>=16 junk)
        short8 v11 = *(const short8*)(vBp + 1280 + hi*128);     // jc1, d 32..47
        __builtin_amdgcn_s_setprio(1);
        accO0 = __builtin_amdgcn_mfma_f32_32x32x16_bf16(pa0, v00, accO0, 0, 0, 0);
        accO0 = __builtin_amdgcn_mfma_f32_32x32x16_bf16(pa1, v10, accO0, 0, 0, 0);
        accO1 = __builtin_amdgcn_mfma_f32_32x32x16_bf16(pa0, v01, accO1, 0, 0, 0);
        accO1 = __builtin_amdgcn_mfma_f32_32x32x16_bf16(pa1, v11, accO1, 0, 0, 0);
        __builtin_amdgcn_s_setprio(0);
        kBp += 4*1536; vBp += 4*1536; dBp += (size_t)SEQ*128;
    }
    rsum += __shfl_xor(rsum, 32);   // partner half-lane holds the other 16 j per tile

    // cross-wave tree reduction
    if (w >= 2) {
        float* Od = Ored[w-2];
        #pragma unroll
        for (int r = 0; r < 16; ++r) {
            int ii = (r & 3) + 8*(r >> 2) + 4*hi;
            Od[ii*48 + li] = accO0[r];
            if (li < 16) Od[ii*48 + 32 + li] = accO1[r];
        }
        if (lane < 32) Lred[w-2][lane] = rsum;
    }
    __syncthreads();
    if (w < 2) {
        const float* Od = Ored[w];
        #pragma unroll
        for (int r = 0; r < 16; ++r) {
            int ii = (r & 3) + 8*(r >> 2) + 4*hi;
            accO0[r] += Od[ii*48 + li];
            accO1[r] += Od[ii*48 + 32 + (li & 15)];
        }
        rsum += Lred[w][li];
    }
    __syncthreads();
    if (w == 1) {
        float* Od = Ored[0];
        #pragma unroll
        for (int r = 0; r < 16; ++r) {
            int ii = (r & 3) + 8*(r >> 2) + 4*hi;
            Od[ii*48 + li] = accO0[r];
            if (li < 16) Od[ii*48 + 32 + li] = accO1[r];
        }
        if (lane < 32) Lred[0][lane] = rsum;
    }
    __syncthreads();
    if (w == 0) {
        float* Od = Ored[0];
        #pragma unroll
        for (int r = 0; r < 16; ++r) {
            int ii = (r & 3) + 8*(r >> 2) + 4*hi;
            Od[ii*48 + li] += accO0[r];
            if (li < 16) Od[ii*48 + 32 + li] += accO1[r];
        }
        if (lane < 32) Lred[0][lane] += rsum;
    }
    __syncthreads();
    // all waves: normalize + coalesced int4 store of the 32x48 tile
    for (int c = t; c < 192; c += 256) {
        int r = c / 6, d8 = (c % 6)*8;
        float inv = 1.0f / Lred[0][r];
        const float* src = &Ored[0][r*48 + d8];
        short o[8];
        #pragma unroll
        for (int e = 0; e < 8; ++e) o[e] = f2b(src[e]*inv);
        *(int4*)(aob + ((size_t)(bi*SEQ) + i0 + r)*DM + hh*HD + d8) = *(const int4*)o;
    }
}

// ---------------- K4: MFMA GEMM out = aob @ Wout + b_out (64x128, pipelined k-loop)
__global__ __launch_bounds__(256) void k_out(const short* __restrict__ aob,
    const short* __restrict__ WT, const void* __restrict__ bout,
    void* __restrict__ out, const void* __restrict__ x)
{
    __shared__ __align__(16) short As[64*72];
    __shared__ __align__(16) short Bs[128*72];
    const int isf = detect_isf(x);
    const int t = threadIdx.x;
    const int w = t >> 6, lane = t & 63, L = lane & 15, quad = lane >> 4;
    const int mt = blockIdx.x / 3, nt = blockIdx.x % 3;
    const int row0 = mt*64, col0 = nt*128;
    const int wm = w & 1, wn = w >> 1;
    float4v acc[2][4] = {};
    int4 rA[2], rB[4];
    {
        #pragma unroll
        for (int ci = 0; ci < 2; ++ci) {
            int c = t + ci*256; int row = c >> 3, k8 = c & 7;
            rA[ci] = *(const int4*)(aob + (size_t)(row0+row)*DM + k8*8);
        }
        #pragma unroll
        for (int ci = 0; ci < 4; ++ci) {
            int c = t + ci*256; int row = c >> 3, k8 = c & 7;
            rB[ci] = *(const int4*)(WT + (size_t)(col0+row)*DM + k8*8);
        }
    }
    for (int ks = 0; ks < 6; ++ks) {
        __syncthreads();
        #pragma unroll
        for (int ci = 0; ci < 2; ++ci) {
            int c = t + ci*256; int row = c >> 3, k8 = c & 7;
            *(int4*)(&As[row*72 + k8*8]) = rA[ci];
        }
        #pragma unroll
        for (int ci = 0; ci < 4; ++ci) {
            int c = t + ci*256; int row = c >> 3, k8 = c & 7;
            *(int4*)(&Bs[row*72 + k8*8]) = rB[ci];
        }
        __syncthreads();
        if (ks < 5) {
            const int k0 = (ks+1)*64;
            #pragma unroll
            for (int ci = 0; ci < 2; ++ci) {
                int c = t + ci*256; int row = c >> 3, k8 = c & 7;
                rA[ci] = *(const int4*)(aob + (size_t)(row0+row)*DM + k0 + k8*8);
            }
            #pragma unroll
            for (int ci = 0; ci < 4; ++ci) {
                int c = t + ci*256; int row = c >> 3, k8 = c & 7;
                rB[ci] = *(const int4*)(WT + (size_t)(col0+row)*DM + k0 + k8*8);
            }
        }
        #pragma unroll
        for (int kc = 0; kc < 2; ++kc) {
            short8 a0 = *(const short8*)(&As[(32*wm + L)*72 + kc*32 + quad*8]);
            short8 a1 = *(const short8*)(&As[(32*wm + 16 + L)*72 + kc*32 + quad*8]);
            #pragma unroll
            for (int ni = 0; ni < 4; ++ni) {
                short8 bf = *(const short8*)(&Bs[(64*wn + 16*ni + L)*72 + kc*32 + quad*8]);
                acc[0][ni] = __builtin_amdgcn_mfma_f32_16x16x32_bf16(a0, bf, acc[0][ni], 0, 0, 0);
                acc[1][ni] = __builtin_amdgcn_mfma_f32_16x16x32_bf16(a1, bf, acc[1][ni], 0, 0, 0);
            }
        }
    }
    #pragma unroll
    for (int mi = 0; mi < 2; ++mi) {
        #pragma unroll
        for (int ni = 0; ni < 4; ++ni) {
            int col_g = col0 + 64*wn + 16*ni + L;
            float bv = ldin(bout, col_g, isf);
            #pragma unroll
            for (int r = 0; r < 4; ++r) {
                int row_g = row0 + 32*wm + 16*mi + quad*4 + r;
                size_t oi = (size_t)row_g*DM + col_g;
                float val = acc[mi][ni][r] + bv;
                if (isf) ((float*)out)[oi] = val;
                else     ((bf16*)out)[oi]  = __float2bfloat16(val);
            }
        }
    }
}

extern "C" void kernel_launch(void* const* d_in, const int* in_sizes, int n_in,
                              void* d_out, int out_size, void* d_ws, size_t ws_size,
                              hipStream_t stream) {
    const void* x      = d_in[0];
    const void* coords = d_in[1];
    const void* Wqkv   = d_in[2];
    const void* bqkv   = d_in[3];
    const void* Wdist  = d_in[4];
    const void* bdist  = d_in[5];
    const void* Wout   = d_in[6];
    const void* bout   = d_in[7];

    short* qg3   = (short*)d_ws;                       // 16*64*1536 = 1,572,864
    short* kg3   = qg3  + (size_t)1572864;
    short* vg3   = kg3  + (size_t)1572864;             // + 256 overread pad
    short* dist8 = vg3  + (size_t)1573120;             // 2*512*2048*4 = 8,388,608
    short* aob   = dist8 + (size_t)8388608;
    short* WqT   = aob  + (size_t)1572864;
    short* WoT   = WqT  + (size_t)442368;

    k_wt<<<dim3(432), dim3(256), 0, stream>>>(x, Wqkv, WqT);
    k_qkv_dist<<<dim3(1232), dim3(256), 0, stream>>>(x, coords, WqT, bqkv, Wout,
                                                     qg3, kg3, vg3, dist8, WoT);
    k_attn<<<dim3(1024), dim3(256), 0, stream>>>(qg3, kg3, vg3, dist8, Wdist, bdist, aob, x);
    k_out<<<dim3(192), dim3(256), 0, stream>>>(aob, WoT, bout, d_out, x);
}

// Round 10
// 156.614 us; speedup vs baseline: 1.0246x; 1.0246x over previous
//
#include <hip/hip_runtime.h>
#include <hip/hip_bf16.h>

#define NB 2
#define SEQ 2048
#define DM 384
#define NH 8
#define HD 48
#define QKVN 1152

typedef __hip_bfloat16 bf16;
typedef __attribute__((ext_vector_type(8))) short short8;
typedef __attribute__((ext_vector_type(4))) float float4v;
typedef __attribute__((ext_vector_type(16))) float f32x16;

static __device__ __forceinline__ float bf2f(bf16 v){ return __bfloat162float(v); }
static __device__ __forceinline__ float ldin(const void* p, size_t i, int isf){
    return isf ? ((const float*)p)[i] : bf2f(((const bf16*)p)[i]);
}
// fp32 -> bf16 bits, RNE
static __device__ __forceinline__ short f2b(float f){
    union { float f; unsigned u; } a; a.f = f;
    unsigned r = a.u + 0x7FFFu + ((a.u >> 16) & 1u);
    return (short)(r >> 16);
}
// packed fp32x2 -> bf16x2 (v_cvt_pk_bf16_f32)
static __device__ __forceinline__ unsigned pk2(float a, float b){
    union { __hip_bfloat162 h; unsigned u; } r;
    r.h = __float22bfloat162_rn(float2{a, b});
    return r.u;
}
static __device__ __forceinline__ float bflo(unsigned u){
    union { unsigned u; float f; } a; a.u = u << 16; return a.f;
}
static __device__ __forceinline__ float bfhi(unsigned u){
    union { unsigned u; float f; } a; a.u = u & 0xFFFF0000u; return a.f;
}
static __device__ __forceinline__ short8 u4pack(unsigned w0, unsigned w1, unsigned w2, unsigned w3){
    union { unsigned u[4]; short8 s; } r; r.u[0]=w0; r.u[1]=w1; r.u[2]=w2; r.u[3]=w3; return r.s;
}
// per-block input dtype probe (0 = bf16, 1 = fp32); wave-uniform
static __device__ __forceinline__ int detect_isf(const void* x){
    const unsigned short* xb = (const unsigned short*)x;
    int l = threadIdx.x & 63;
    union { unsigned u; float f; } a; a.u = ((unsigned)xb[2*l]) << 16;
    float ab = fabsf(a.f);
    int good = (a.f == 0.0f) || (ab > 9.765625e-4f && ab < 1024.0f);
    unsigned long long m = __ballot(good);
    return (__popcll(m) >= 32) ? 0 : 1;
}
// A-operand fragment: 8 consecutive elems of row `row` at k-offset k (bf16 or fp32 input)
static __device__ __forceinline__ short8 ldfragA(const void* x, size_t row, int k, int isf){
    size_t off = row*DM + k;
    if (isf) {
        const float* xf = (const float*)x + off;
        short o[8];
        #pragma unroll
        for (int e = 0; e < 8; ++e) o[e] = f2b(xf[e]);
        return *(const short8*)o;
    }
    return *(const short8*)((const short*)x + off);
}

// ---------------- K1: WqT transpose only
__global__ __launch_bounds__(256) void k_wt(const void* __restrict__ x,
    const void* __restrict__ Wqkv, short* __restrict__ WqT)
{
    const int isf = detect_isf(x);
    const int t = threadIdx.x;
    const int b = blockIdx.x;          // 0..431
    const int kt = b / 36, nt = b % 36;
    const int k0 = kt*32, n0 = nt*32;
    __shared__ float Ls[32][33];
    for (int idx = t; idx < 1024; idx += 256) {
        int r = idx >> 5, c = idx & 31;
        Ls[r][c] = ldin(Wqkv, (size_t)(k0+r)*QKVN + n0 + c, isf);
    }
    __syncthreads();
    for (int idx = t; idx < 1024; idx += 256) {
        int r2 = idx >> 5, c2 = idx & 31;
        WqT[(size_t)(n0+r2)*DM + k0 + c2] = f2b(Ls[c2][r2]);
    }
}

// ---------------- K2: fused {qkv GEMM [0,576) | dist8 [576,1088) | WoT [1088,1232)}.
// R9 post-mortem: manual reg-prefetch pipelining REGRESSED (45->53 us, WRITE_SIZE 2.4x —
// spill traffic; compiler's own hoisting was better). This round removes the barrier
// chain entirely instead: both GEMM operands are fragment-contiguous in global memory
// (A = x[row][k..k+8], B = WqT[col][k..k+8]) so the k-loop needs NO LDS staging and NO
// __syncthreads — waves run free, loads hoist arbitrarily, L1 absorbs the 2x wm/wn
// operand duplication. Only the epilogue reorg uses LDS (2 barriers total, was 14).
// Layouts (unchanged):
// qg3/kg3: [bh][t32(64)][dc(3)][hi(2)][tok(32)][e(8)]  elem = X[tok][dc*16 + hi*8 + e]
// vg3:     [bh][jt(64)][jc(2)]{ dt0:[hi][32 d][e8] , dt1:[hi][16 d][e8] } 1536 s/tile.
//          slot (hi,e) holds token j = jc*16 + (e&3) + 8*(e>>2) + 4*hi (verified 32x32
//          C-row order) so PV's A-operand is the raw sacc register order — no cross-lane.
// dist8: [b][jg = j>>2 (512)][i(2048)][jj(4)] bf16 (R6 mapping — best measured).
__global__ __launch_bounds__(256) void k_qkv_dist(const void* __restrict__ x,
    const void* __restrict__ coords,
    const short* __restrict__ WT, const void* __restrict__ bqkv,
    const void* __restrict__ Wout,
    short* __restrict__ qg3, short* __restrict__ kg3, short* __restrict__ vg3,
    short* __restrict__ dist8, short* __restrict__ WoT)
{
    __shared__ __align__(16) short Ep[128*72];   // epilogue reorg buffer only
    __shared__ float cjx[16], cjy[16], cjz[16];
    const int isf = detect_isf(x);
    const int t = threadIdx.x;
    const int bid = blockIdx.x;
    if (bid >= 1088) {
        // ---- WoT transpose section (consumed by k_out, two kernels later)
        const int b = bid - 1088;        // 0..143
        const int kt = b / 12, nt = b % 12;
        const int k0 = kt*32, n0 = nt*32;
        float (*Ls)[33] = (float(*)[33])Ep;   // alias (32*33*4 B = 4.2 KB fits)
        for (int idx = t; idx < 1024; idx += 256) {
            int r = idx >> 5, c = idx & 31;
            Ls[r][c] = ldin(Wout, (size_t)(k0+r)*DM + n0 + c, isf);
        }
        __syncthreads();
        for (int idx = t; idx < 1024; idx += 256) {
            int r2 = idx >> 5, c2 = idx & 31;
            WoT[(size_t)(n0+r2)*DM + k0 + c2] = f2b(Ls[c2][r2]);
        }
        return;
    }
    if (bid >= 576) {
        // ---- dist section (R6 mapping)
        const int b = bid - 576;             // 0..511
        const int bb = b >> 8;               // batch
        const int jg = (b >> 1) & 127;       // 16-j group
        const int j0 = jg * 16;
        const int ih = (b & 1) * 1024;       // i-half
        if (t < 16) {
            int gj = (bb*SEQ + j0 + t)*3;
            cjx[t] = ldin(coords, gj, isf);
            cjy[t] = ldin(coords, gj+1, isf);
            cjz[t] = ldin(coords, gj+2, isf);
        }
        __syncthreads();
        #pragma unroll
        for (int k = 0; k < 4; ++k) {
            int i = ih + k*256 + t;
            int gi = (bb*SEQ + i)*3;
            float px = ldin(coords, gi, isf), py = ldin(coords, gi+1, isf), pz = ldin(coords, gi+2, isf);
            short o[16];
            #pragma unroll
            for (int e = 0; e < 16; ++e) {
                float dx = px - cjx[e], dy = py - cjy[e], dz = pz - cjz[e];
                o[e] = f2b(sqrtf(dx*dx + dy*dy + dz*dz));
            }
            short* dst = dist8 + (((size_t)bb*512 + (size_t)jg*4)*SEQ + i)*4;
            *(int2*)(dst)          = *(const int2*)(o);
            *(int2*)(dst + SEQ*4)  = *(const int2*)(o + 4);
            *(int2*)(dst + SEQ*8)  = *(const int2*)(o + 8);
            *(int2*)(dst + SEQ*12) = *(const int2*)(o + 12);
        }
        return;
    }
    // ---- qkv GEMM section: zero-LDS, zero-barrier k-loop
    const int w = t >> 6, lane = t & 63, L = lane & 15, quad = lane >> 4;
    const int mt = bid / 9, nt = bid % 9;
    const int row0 = mt*64, col0 = nt*128;
    const int wm = w & 1, wn = w >> 1;
    float4v acc[2][4] = {};
    const size_t rA0 = (size_t)(row0 + 32*wm + L);
    const size_t rA1 = rA0 + 16;
    const short* wB = WT + (size_t)(col0 + 64*wn + L)*DM;
    #pragma unroll 4
    for (int kk = 0; kk < 12; ++kk) {
        const int k0 = kk*32 + quad*8;
        short8 a0 = ldfragA(x, rA0, k0, isf);
        short8 a1 = ldfragA(x, rA1, k0, isf);
        #pragma unroll
        for (int ni = 0; ni < 4; ++ni) {
            short8 bf = *(const short8*)(wB + (size_t)(16*ni)*DM + k0);
            acc[0][ni] = __builtin_amdgcn_mfma_f32_16x16x32_bf16(a0, bf, acc[0][ni], 0, 0, 0);
            acc[1][ni] = __builtin_amdgcn_mfma_f32_16x16x32_bf16(a1, bf, acc[1][ni], 0, 0, 0);
        }
    }
    const int which = col0 / DM;     // uniform per block (0=q,1=k,2=v)
    const int cbase = col0 % DM;
    if (which < 2) {
        // row-major Ep[64 tokens][136]
        #pragma unroll
        for (int mi = 0; mi < 2; ++mi)
            #pragma unroll
            for (int ni = 0; ni < 4; ++ni) {
                int col_l = 64*wn + 16*ni + L;
                float bv = ldin(bqkv, col0 + col_l, isf);
                #pragma unroll
                for (int r = 0; r < 4; ++r) {
                    int row_l = 32*wm + 16*mi + quad*4 + r;
                    Ep[row_l*136 + col_l] = f2b(acc[mi][ni][r] + bv);
                }
            }
        __syncthreads();
        short* dst = which ? kg3 : qg3;
        for (int c = t; c < 1024; c += 256) {
            int row_l = c >> 4, col_l = (c & 15)*8;   // 8 consecutive d, one token
            int row_g = row0 + row_l;
            int bi = row_g >> 11, nn = row_g & (SEQ-1);
            int c2 = cbase + col_l;
            int hh = c2/HD, dh = c2%HD;
            int bh = bi*NH + hh;
            int dc = dh >> 4, hi = (dh >> 3) & 1;
            size_t dstoff = ((size_t)bh*64 + (nn>>5))*1536 + (size_t)((dc*2 + hi)*256 + (nn&31)*8);
            *(int4*)(dst + dstoff) = *(const int4*)(&Ep[row_l*136 + col_l]);
        }
    } else {
        // col-major Ep[128 cols][72 tokens]
        #pragma unroll
        for (int mi = 0; mi < 2; ++mi)
            #pragma unroll
            for (int ni = 0; ni < 4; ++ni) {
                int col_l = 64*wn + 16*ni + L;
                float bv = ldin(bqkv, col0 + col_l, isf);
                #pragma unroll
                for (int r = 0; r < 4; ++r) {
                    int row_l = 32*wm + 16*mi + quad*4 + r;
                    Ep[col_l*72 + row_l] = f2b(acc[mi][ni][r] + bv);
                }
            }
        __syncthreads();
        for (int c = t; c < 1024; c += 256) {
            int col_l = c >> 3, row8 = (c & 7)*8;     // 8 consecutive tokens, one d
            int row_g = row0 + row8;
            int bi = row_g >> 11, nn = row_g & (SEQ-1);
            int c2 = cbase + col_l;
            int hh = c2/HD, dh = c2%HD;
            int bh = bi*NH + hh;
            int jt = nn >> 5, jc = (nn >> 4) & 1;
            int ehalf = ((nn >> 3) & 1)*4;            // e>>2 half of the slot
            int dt = dh >> 5, dp = dh & 31;           // d-tile 0: 32 cols, d-tile 1: 16 cols
            int hstride = dt ? 128 : 256;
            size_t base = ((size_t)bh*64 + jt)*1536 + (size_t)(jc*768 + dt*512 + dp*8 + ehalf);
            *(int2*)(vg3 + base)           = *(const int2*)(&Ep[col_l*72 + row8]);
            *(int2*)(vg3 + base + hstride) = *(const int2*)(&Ep[col_l*72 + row8 + 4]);
        }
    }
}

// ---------------- K3: flash attention on 32x32x16 MFMA, 32 i per block, grid 1024
// 4/CU = 16 waves/CU. 4 waves split the j-range (wave w: tiles 4s+w). QK^T: 3 pad-free
// K=16 MFMA; sacc: i = lane&31, slot r -> j = jb + (r&3) + 8*(r>>2) + 4*hi (m74/m101).
// PV: pa in raw sacc register order (V slot-permuted at prep). setprio around MFMA
// clusters (independent waves — m191 regime). wd/bd computed inline from Wdist/bdist.
// Swizzle: XCD x hosts all 8 heads of one (batch, 16-it band).
__global__ __launch_bounds__(256, 4) void k_attn(
    const short* __restrict__ qg3, const short* __restrict__ kg3, const short* __restrict__ vg3,
    const short* __restrict__ dist8, const void* __restrict__ Wdist,
    const void* __restrict__ bdist, short* __restrict__ aob, const void* __restrict__ x)
{
    __shared__ float Ored[2][32*48];
    __shared__ float Lred[2][32];
    const int isf = detect_isf(x);
    const int t = threadIdx.x;
    const int w = t >> 6, lane = t & 63;
    const int li = lane & 31, hi = lane >> 5;
    const int xcd  = blockIdx.x & 7;
    const int slot = blockIdx.x >> 3;        // 0..127
    const int bi   = xcd >> 2;               // batch
    const int band = xcd & 3;                // 16-it band
    const int hh   = slot & 7;
    const int it   = band*16 + (slot >> 3);  // 0..63
    const int bh   = bi*NH + hh;
    const int i0 = it*32;
    const float log2e = 1.4426950408889634f;
    const float scale2 = 0.14433756729740643f * log2e;
    const float wd = ldin(Wdist, hh, isf) * log2e;
    const float bd = ldin(bdist, hh, isf) * log2e;

    const short* qB = qg3 + ((size_t)bh*64 + it)*1536 + hi*256 + li*8;
    const short8 qf0 = *(const short8*)(qB);
    const short8 qf1 = *(const short8*)(qB + 512);
    const short8 qf2 = *(const short8*)(qB + 1024);

    f32x16 accO0 = {}, accO1 = {};
    float rsum = 0.0f;

    const short* kBp = kg3 + ((size_t)bh*64 + w)*1536 + hi*256 + li*8;
    const short* vBp = vg3 + ((size_t)bh*64 + w)*1536 + li*8;
    const short* dBp = dist8 + (((size_t)bi*512 + (size_t)w*8 + hi)*SEQ + i0 + li)*4;

    for (int s = 0; s < 16; ++s) {
        short8 kf0 = *(const short8*)(kBp);
        short8 kf1 = *(const short8*)(kBp + 512);
        short8 kf2 = *(const short8*)(kBp + 1024);
        int2 du0 = *(const int2*)(dBp);
        int2 du1 = *(const int2*)(dBp + SEQ*8);
        int2 du2 = *(const int2*)(dBp + SEQ*16);
        int2 du3 = *(const int2*)(dBp + SEQ*24);
        f32x16 sacc = {};
        __builtin_amdgcn_s_setprio(1);
        sacc = __builtin_amdgcn_mfma_f32_32x32x16_bf16(kf0, qf0, sacc, 0, 0, 0);
        sacc = __builtin_amdgcn_mfma_f32_32x32x16_bf16(kf1, qf1, sacc, 0, 0, 0);
        sacc = __builtin_amdgcn_mfma_f32_32x32x16_bf16(kf2, qf2, sacc, 0, 0, 0);
        __builtin_amdgcn_s_setprio(0);
        float p[16];
        #pragma unroll
        for (int rq = 0; rq < 4; ++rq) {
            int2 du = rq == 0 ? du0 : rq == 1 ? du1 : rq == 2 ? du2 : du3;
            float d0 = bflo((unsigned)du.x), d1 = bfhi((unsigned)du.x);
            float d2 = bflo((unsigned)du.y), d3 = bfhi((unsigned)du.y);
            p[4*rq+0] = __builtin_amdgcn_exp2f(fmaf(sacc[4*rq+0], scale2, fmaf(d0, wd, bd)));
            p[4*rq+1] = __builtin_amdgcn_exp2f(fmaf(sacc[4*rq+1], scale2, fmaf(d1, wd, bd)));
            p[4*rq+2] = __builtin_amdgcn_exp2f(fmaf(sacc[4*rq+2], scale2, fmaf(d2, wd, bd)));
            p[4*rq+3] = __builtin_amdgcn_exp2f(fmaf(sacc[4*rq+3], scale2, fmaf(d3, wd, bd)));
            rsum += (p[4*rq+0] + p[4*rq+1]) + (p[4*rq+2] + p[4*rq+3]);
        }
        short8 pa0 = u4pack(pk2(p[0],p[1]),  pk2(p[2],p[3]),  pk2(p[4],p[5]),   pk2(p[6],p[7]));
        short8 pa1 = u4pack(pk2(p[8],p[9]),  pk2(p[10],p[11]),pk2(p[12],p[13]), pk2(p[14],p[15]));
        short8 v00 = *(const short8*)(vBp + hi*256);            // jc0, d 0..31
        short8 v10 = *(const short8*)(vBp + 768 + hi*256);      // jc1, d 0..31
        short8 v01 = *(const short8*)(vBp + 512 + hi*128);      // jc0, d 32..47 (cols>=16 junk)
        short8 v11 = *(const short8*)(vBp + 1280 + hi*128);     // jc1, d 32..47
        __builtin_amdgcn_s_setprio(1);
        accO0 = __builtin_amdgcn_mfma_f32_32x32x16_bf16(pa0, v00, accO0, 0, 0, 0);
        accO0 = __builtin_amdgcn_mfma_f32_32x32x16_bf16(pa1, v10, accO0, 0, 0, 0);
        accO1 = __builtin_amdgcn_mfma_f32_32x32x16_bf16(pa0, v01, accO1, 0, 0, 0);
        accO1 = __builtin_amdgcn_mfma_f32_32x32x16_bf16(pa1, v11, accO1, 0, 0, 0);
        __builtin_amdgcn_s_setprio(0);
        kBp += 4*1536; vBp += 4*1536; dBp += (size_t)SEQ*128;
    }
    rsum += __shfl_xor(rsum, 32);   // partner half-lane holds the other 16 j per tile

    // cross-wave tree reduction
    if (w >= 2) {
        float* Od = Ored[w-2];
        #pragma unroll
        for (int r = 0; r < 16; ++r) {
            int ii = (r & 3) + 8*(r >> 2) + 4*hi;
            Od[ii*48 + li] = accO0[r];
            if (li < 16) Od[ii*48 + 32 + li] = accO1[r];
        }
        if (lane < 32) Lred[w-2][lane] = rsum;
    }
    __syncthreads();
    if (w < 2) {
        const float* Od = Ored[w];
        #pragma unroll
        for (int r = 0; r < 16; ++r) {
            int ii = (r & 3) + 8*(r >> 2) + 4*hi;
            accO0[r] += Od[ii*48 + li];
            accO1[r] += Od[ii*48 + 32 + (li & 15)];
        }
        rsum += Lred[w][li];
    }
    __syncthreads();
    if (w == 1) {
        float* Od = Ored[0];
        #pragma unroll
        for (int r = 0; r < 16; ++r) {
            int ii = (r & 3) + 8*(r >> 2) + 4*hi;
            Od[ii*48 + li] = accO0[r];
            if (li < 16) Od[ii*48 + 32 + li] = accO1[r];
        }
        if (lane < 32) Lred[0][lane] = rsum;
    }
    __syncthreads();
    if (w == 0) {
        float* Od = Ored[0];
        #pragma unroll
        for (int r = 0; r < 16; ++r) {
            int ii = (r & 3) + 8*(r >> 2) + 4*hi;
            Od[ii*48 + li] += accO0[r];
            if (li < 16) Od[ii*48 + 32 + li] += accO1[r];
        }
        if (lane < 32) Lred[0][lane] += rsum;
    }
    __syncthreads();
    // all waves: normalize + coalesced int4 store of the 32x48 tile
    for (int c = t; c < 192; c += 256) {
        int r = c / 6, d8 = (c % 6)*8;
        float inv = 1.0f / Lred[0][r];
        const float* src = &Ored[0][r*48 + d8];
        short o[8];
        #pragma unroll
        for (int e = 0; e < 8; ++e) o[e] = f2b(src[e]*inv);
        *(int4*)(aob + ((size_t)(bi*SEQ) + i0 + r)*DM + hh*HD + d8) = *(const int4*)o;
    }
}

// ---------------- K4: MFMA GEMM out = aob @ Wout + b_out — LDS-free, barrier-free.
// 4 independent waves per block, each owning a 16x64 tile (grid 384 = 6 waves/CU).
// Both operands fragment-contiguous (aob row-major, WoT pre-transposed).
__global__ __launch_bounds__(256) void k_out(const short* __restrict__ aob,
    const short* __restrict__ WT, const void* __restrict__ bout,
    void* __restrict__ out, const void* __restrict__ x)
{
    const int isf = detect_isf(x);
    const int t = threadIdx.x;
    const int w = t >> 6, lane = t & 63, L = lane & 15, quad = lane >> 4;
    const int mt = (blockIdx.x / 6)*4 + w;   // 0..255 (16-row tiles)
    const int nt = blockIdx.x % 6;           // 64-col tiles
    const int row0 = mt*16, col0 = nt*64;
    float4v acc[4] = {};
    const short* aB = aob + (size_t)(row0 + L)*DM;
    const short* wB = WT + (size_t)(col0 + L)*DM;
    #pragma unroll 4
    for (int kk = 0; kk < 12; ++kk) {
        const int k0 = kk*32 + quad*8;
        short8 a0 = *(const short8*)(aB + k0);
        #pragma unroll
        for (int ni = 0; ni < 4; ++ni) {
            short8 bf = *(const short8*)(wB + (size_t)(16*ni)*DM + k0);
            acc[ni] = __builtin_amdgcn_mfma_f32_16x16x32_bf16(a0, bf, acc[ni], 0, 0, 0);
        }
    }
    #pragma unroll
    for (int ni = 0; ni < 4; ++ni) {
        int col_g = col0 + 16*ni + L;
        float bv = ldin(bout, col_g, isf);
        #pragma unroll
        for (int r = 0; r < 4; ++r) {
            int row_g = row0 + quad*4 + r;
            size_t oi = (size_t)row_g*DM + col_g;
            float val = acc[ni][r] + bv;
            if (isf) ((float*)out)[oi] = val;
            else     ((bf16*)out)[oi]  = __float2bfloat16(val);
        }
    }
}

extern "C" void kernel_launch(void* const* d_in, const int* in_sizes, int n_in,
                              void* d_out, int out_size, void* d_ws, size_t ws_size,
                              hipStream_t stream) {
    const void* x      = d_in[0];
    const void* coords = d_in[1];
    const void* Wqkv   = d_in[2];
    const void* bqkv   = d_in[3];
    const void* Wdist  = d_in[4];
    const void* bdist  = d_in[5];
    const void* Wout   = d_in[6];
    const void* bout   = d_in[7];

    short* qg3   = (short*)d_ws;                       // 16*64*1536 = 1,572,864
    short* kg3   = qg3  + (size_t)1572864;
    short* vg3   = kg3  + (size_t)1572864;             // + 256 overread pad
    short* dist8 = vg3  + (size_t)1573120;             // 2*512*2048*4 = 8,388,608
    short* aob   = dist8 + (size_t)8388608;
    short* WqT   = aob  + (size_t)1572864;
    short* WoT   = WqT  + (size_t)442368;

    k_wt<<<dim3(432), dim3(256), 0, stream>>>(x, Wqkv, WqT);
    k_qkv_dist<<<dim3(1232), dim3(256), 0, stream>>>(x, coords, WqT, bqkv, Wout,
                                                     qg3, kg3, vg3, dist8, WoT);
    k_attn<<<dim3(1024), dim3(256), 0, stream>>>(qg3, kg3, vg3, dist8, Wdist, bdist, aob, x);
    k_out<<<dim3(384), dim3(256), 0, stream>>>(aob, WoT, bout, d_out, x);
}

// Round 11
// 145.029 us; speedup vs baseline: 1.1065x; 1.0799x over previous
//
#include <hip/hip_runtime.h>
#include <hip/hip_bf16.h>

#define NB 2
#define SEQ 2048
#define DM 384
#define NH 8
#define HD 48
#define QKVN 1152

typedef __hip_bfloat16 bf16;
typedef __attribute__((ext_vector_type(8))) short short8;
typedef __attribute__((ext_vector_type(4))) float float4v;
typedef __attribute__((ext_vector_type(16))) float f32x16;

static __device__ __forceinline__ float bf2f(bf16 v){ return __bfloat162float(v); }
static __device__ __forceinline__ float ldin(const void* p, size_t i, int isf){
    return isf ? ((const float*)p)[i] : bf2f(((const bf16*)p)[i]);
}
// fp32 -> bf16 bits, RNE
static __device__ __forceinline__ short f2b(float f){
    union { float f; unsigned u; } a; a.f = f;
    unsigned r = a.u + 0x7FFFu + ((a.u >> 16) & 1u);
    return (short)(r >> 16);
}
// packed fp32x2 -> bf16x2 (v_cvt_pk_bf16_f32)
static __device__ __forceinline__ unsigned pk2(float a, float b){
    union { __hip_bfloat162 h; unsigned u; } r;
    r.h = __float22bfloat162_rn(float2{a, b});
    return r.u;
}
static __device__ __forceinline__ float bflo(unsigned u){
    union { unsigned u; float f; } a; a.u = u << 16; return a.f;
}
static __device__ __forceinline__ float bfhi(unsigned u){
    union { unsigned u; float f; } a; a.u = u & 0xFFFF0000u; return a.f;
}
static __device__ __forceinline__ short8 u4pack(unsigned w0, unsigned w1, unsigned w2, unsigned w3){
    union { unsigned u[4]; short8 s; } r; r.u[0]=w0; r.u[1]=w1; r.u[2]=w2; r.u[3]=w3; return r.s;
}
// per-block input dtype probe (0 = bf16, 1 = fp32); wave-uniform
static __device__ __forceinline__ int detect_isf(const void* x){
    const unsigned short* xb = (const unsigned short*)x;
    int l = threadIdx.x & 63;
    union { unsigned u; float f; } a; a.u = ((unsigned)xb[2*l]) << 16;
    float ab = fabsf(a.f);
    int good = (a.f == 0.0f) || (ab > 9.765625e-4f && ab < 1024.0f);
    unsigned long long m = __ballot(good);
    return (__popcll(m) >= 32) ? 0 : 1;
}

// ---------------- K1: W^T transposes + bias misc (tiny, runs first)
// [0,432) WqT | [432,576) WoT | [576,583) misc
__global__ __launch_bounds__(256) void k_wt(const void* __restrict__ x,
    const void* __restrict__ Wqkv, const void* __restrict__ Wout,
    const void* __restrict__ bqkv, const void* __restrict__ bout,
    const void* __restrict__ Wdist, const void* __restrict__ bdist,
    short* __restrict__ WqT, short* __restrict__ WoT,
    float* __restrict__ bqf, float* __restrict__ bof,
    float* __restrict__ wdf, float* __restrict__ bdf)
{
    const int isf = detect_isf(x);
    const int t = threadIdx.x;
    const int b = blockIdx.x;
    if (b < 576) {
        int bb, NW; const void* W; short* WT;
        if (b < 432) { bb = b;       NW = QKVN; W = Wqkv; WT = WqT; }
        else         { bb = b - 432; NW = DM;   W = Wout; WT = WoT; }
        int ntiles = NW >> 5;
        int kt = bb / ntiles, nt = bb % ntiles;
        int k0 = kt*32, n0 = nt*32;
        __shared__ float Ls[32][33];
        for (int idx = t; idx < 1024; idx += 256) {
            int r = idx >> 5, c = idx & 31;
            Ls[r][c] = ldin(W, (size_t)(k0+r)*NW + n0 + c, isf);
        }
        __syncthreads();
        for (int idx = t; idx < 1024; idx += 256) {
            int r2 = idx >> 5, c2 = idx & 31;
            WT[(size_t)(n0+r2)*DM + k0 + c2] = f2b(Ls[c2][r2]);
        }
    } else {
        int idx = (b - 576)*256 + t;
        const float log2e = 1.4426950408889634f;
        if (idx < QKVN) bqf[idx] = ldin(bqkv, idx, isf);
        else if (idx < QKVN + DM) bof[idx - QKVN] = ldin(bout, idx - QKVN, isf);
        else if (idx < QKVN + DM + NH) wdf[idx - QKVN - DM] = ldin(Wdist, idx - QKVN - DM, isf)*log2e;
        else if (idx < QKVN + DM + 2*NH) bdf[idx - QKVN - DM - NH] = ldin(bdist, idx - QKVN - DM - NH, isf)*log2e;
    }
}

// ---------------- K2: fused {qkv GEMM | dist8} — independent sections co-scheduled.
// (R6 configuration — best measured total, 143.8 us. All 1088 blocks co-resident:
// LDS caps at 5 blocks/CU > 1088/256, so dist fills GEMM latency stalls regardless of
// dispatch order.)
// qkv section: GEMM qkv = x @ Wqkv + b (x read directly, converted during As staging);
// qg3/kg3: [bh][t32(64)][dc(3)][hi(2)][tok(32)][e(8)]  elem = X[tok][dc*16 + hi*8 + e]
// vg3:     [bh][jt(64)][jc(2)]{ dt0:[hi][32 d][e8] , dt1:[hi][16 d][e8] } 1536 s/tile.
//          slot (hi,e) holds token j = jc*16 + (e&3) + 8*(e>>2) + 4*hi (verified 32x32
//          C-row order) so PV's A-operand is the raw sacc register order — no cross-lane.
// dist section: dist8[b][jg = j>>2 (512)][i(2048)][jj(4)] bf16. Precomputed once, shared
//   across 8 heads (round-2: fusing into attn makes it trans-pipe-bound, 73.7 us).
__global__ __launch_bounds__(256) void k_qkv_dist(const void* __restrict__ x,
    const void* __restrict__ coords,
    const short* __restrict__ WT, const float* __restrict__ bias,
    short* __restrict__ qg3, short* __restrict__ kg3, short* __restrict__ vg3,
    short* __restrict__ dist8)
{
    __shared__ __align__(16) short As[64*72];
    __shared__ __align__(16) short Bs[128*72];   // reused as epilogue buffer
    __shared__ float cjx[16], cjy[16], cjz[16];
    const int isf = detect_isf(x);
    const int t = threadIdx.x;
    if (blockIdx.x >= 576) {
        // ---- dist section
        const int b = blockIdx.x - 576;      // 0..511
        const int bb = b >> 8;               // batch
        const int jg = (b >> 1) & 127;       // 16-j group
        const int j0 = jg * 16;
        const int ih = (b & 1) * 1024;       // i-half
        if (t < 16) {
            int gj = (bb*SEQ + j0 + t)*3;
            cjx[t] = ldin(coords, gj, isf);
            cjy[t] = ldin(coords, gj+1, isf);
            cjz[t] = ldin(coords, gj+2, isf);
        }
        __syncthreads();
        #pragma unroll
        for (int k = 0; k < 4; ++k) {
            int i = ih + k*256 + t;
            int gi = (bb*SEQ + i)*3;
            float px = ldin(coords, gi, isf), py = ldin(coords, gi+1, isf), pz = ldin(coords, gi+2, isf);
            short o[16];
            #pragma unroll
            for (int e = 0; e < 16; ++e) {
                float dx = px - cjx[e], dy = py - cjy[e], dz = pz - cjz[e];
                o[e] = f2b(sqrtf(dx*dx + dy*dy + dz*dz));
            }
            // 4 groups of 4 j each: [b][jg*4+g][i][4]
            short* dst = dist8 + (((size_t)bb*512 + (size_t)jg*4)*SEQ + i)*4;
            *(int2*)(dst)          = *(const int2*)(o);
            *(int2*)(dst + SEQ*4)  = *(const int2*)(o + 4);
            *(int2*)(dst + SEQ*8)  = *(const int2*)(o + 8);
            *(int2*)(dst + SEQ*12) = *(const int2*)(o + 12);
        }
        return;
    }
    // ---- qkv GEMM section
    const int w = t >> 6, lane = t & 63, L = lane & 15, quad = lane >> 4;
    const int mt = blockIdx.x / 9, nt = blockIdx.x % 9;
    const int row0 = mt*64, col0 = nt*128;
    const int wm = w & 1, wn = w >> 1;
    float4v acc[2][4] = {};
    for (int k0 = 0; k0 < DM; k0 += 64) {
        __syncthreads();
        for (int c = t; c < 512; c += 256) {
            int row = c >> 3, k8 = c & 7;
            size_t src = (size_t)(row0+row)*DM + k0 + k8*8;
            if (isf) {
                const float* xf = (const float*)x + src;
                short o[8];
                #pragma unroll
                for (int e = 0; e < 8; ++e) o[e] = f2b(xf[e]);
                *(int4*)(&As[row*72 + k8*8]) = *(const int4*)o;
            } else {
                *(int4*)(&As[row*72 + k8*8]) = *(const int4*)((const short*)x + src);
            }
        }
        for (int c = t; c < 1024; c += 256) {
            int row = c >> 3, k8 = c & 7;
            *(int4*)(&Bs[row*72 + k8*8]) = *(const int4*)(WT + (size_t)(col0+row)*DM + k0 + k8*8);
        }
        __syncthreads();
        #pragma unroll
        for (int kc = 0; kc < 2; ++kc) {
            short8 a0 = *(const short8*)(&As[(32*wm + L)*72 + kc*32 + quad*8]);
            short8 a1 = *(const short8*)(&As[(32*wm + 16 + L)*72 + kc*32 + quad*8]);
            #pragma unroll
            for (int ni = 0; ni < 4; ++ni) {
                short8 bf = *(const short8*)(&Bs[(64*wn + 16*ni + L)*72 + kc*32 + quad*8]);
                acc[0][ni] = __builtin_amdgcn_mfma_f32_16x16x32_bf16(a0, bf, acc[0][ni], 0, 0, 0);
                acc[1][ni] = __builtin_amdgcn_mfma_f32_16x16x32_bf16(a1, bf, acc[1][ni], 0, 0, 0);
            }
        }
    }
    const int which = col0 / DM;     // uniform per block (0=q,1=k,2=v)
    const int cbase = col0 % DM;
    short* Ep = Bs;
    __syncthreads();
    if (which < 2) {
        // row-major Ep[64 tokens][136]
        #pragma unroll
        for (int mi = 0; mi < 2; ++mi)
            #pragma unroll
            for (int ni = 0; ni < 4; ++ni) {
                int col_l = 64*wn + 16*ni + L;
                float bv = bias[col0 + col_l];
                #pragma unroll
                for (int r = 0; r < 4; ++r) {
                    int row_l = 32*wm + 16*mi + quad*4 + r;
                    Ep[row_l*136 + col_l] = f2b(acc[mi][ni][r] + bv);
                }
            }
        __syncthreads();
        short* dst = which ? kg3 : qg3;
        for (int c = t; c < 1024; c += 256) {
            int row_l = c >> 4, col_l = (c & 15)*8;   // 8 consecutive d, one token
            int row_g = row0 + row_l;
            int bi = row_g >> 11, nn = row_g & (SEQ-1);
            int c2 = cbase + col_l;
            int hh = c2/HD, dh = c2%HD;
            int bh = bi*NH + hh;
            int dc = dh >> 4, hi = (dh >> 3) & 1;
            size_t dstoff = ((size_t)bh*64 + (nn>>5))*1536 + (size_t)((dc*2 + hi)*256 + (nn&31)*8);
            *(int4*)(dst + dstoff) = *(const int4*)(&Ep[row_l*136 + col_l]);
        }
    } else {
        // col-major Ep[128 cols][72 tokens]
        #pragma unroll
        for (int mi = 0; mi < 2; ++mi)
            #pragma unroll
            for (int ni = 0; ni < 4; ++ni) {
                int col_l = 64*wn + 16*ni + L;
                float bv = bias[col0 + col_l];
                #pragma unroll
                for (int r = 0; r < 4; ++r) {
                    int row_l = 32*wm + 16*mi + quad*4 + r;
                    Ep[col_l*72 + row_l] = f2b(acc[mi][ni][r] + bv);
                }
            }
        __syncthreads();
        for (int c = t; c < 1024; c += 256) {
            int col_l = c >> 3, row8 = (c & 7)*8;     // 8 consecutive tokens, one d
            int row_g = row0 + row8;
            int bi = row_g >> 11, nn = row_g & (SEQ-1);
            int c2 = cbase + col_l;
            int hh = c2/HD, dh = c2%HD;
            int bh = bi*NH + hh;
            int jt = nn >> 5, jc = (nn >> 4) & 1;
            int ehalf = ((nn >> 3) & 1)*4;            // e>>2 half of the slot
            int dt = dh >> 5, dp = dh & 31;           // d-tile 0: 32 cols, d-tile 1: 16 cols
            int hstride = dt ? 128 : 256;
            size_t base = ((size_t)bh*64 + jt)*1536 + (size_t)(jc*768 + dt*512 + dp*8 + ehalf);
            *(int2*)(vg3 + base)           = *(const int2*)(&Ep[col_l*72 + row8]);
            *(int2*)(vg3 + base + hstride) = *(const int2*)(&Ep[col_l*72 + row8 + 4]);
        }
    }
}

// ---------------- K3: flash attention on 32x32x16 MFMA, 32 i per block, grid 1024
// 4/CU = 16 waves/CU (round-3: 512-block version was latency-bound at 2/CU).
// 4 waves split the j-range (wave w: tiles 4s+w). QK^T: 3 pad-free K=16 MFMA; sacc:
// i = lane&31, slot r -> j = jb + (r&3) + 8*(r>>2) + 4*hi (m74/m101). PV: pa in raw sacc
// register order (V slot-permuted at prep). 7 MFMA/iter. setprio around MFMA clusters:
// waves here are barrier-free/independent — the regime where T5 measured +4-7% (m191).
// Swizzle: XCD x hosts all 8 heads of one (batch, 16-it band): dist8 slice (2 MB) shared
// 8x across heads through L2/L3.
__global__ __launch_bounds__(256, 4) void k_attn(
    const short* __restrict__ qg3, const short* __restrict__ kg3, const short* __restrict__ vg3,
    const short* __restrict__ dist8, const float* __restrict__ wdf,
    const float* __restrict__ bdf, short* __restrict__ aob)
{
    __shared__ float Ored[2][32*48];
    __shared__ float Lred[2][32];
    const int t = threadIdx.x;
    const int w = t >> 6, lane = t & 63;
    const int li = lane & 31, hi = lane >> 5;
    const int xcd  = blockIdx.x & 7;
    const int slot = blockIdx.x >> 3;        // 0..127
    const int bi   = xcd >> 2;               // batch
    const int band = xcd & 3;                // 16-it band
    const int hh   = slot & 7;
    const int it   = band*16 + (slot >> 3);  // 0..63
    const int bh   = bi*NH + hh;
    const int i0 = it*32;
    const float scale2 = 0.14433756729740643f * 1.4426950408889634f;
    const float wd = wdf[hh], bd = bdf[hh];     // pre-scaled by log2e

    const short* qB = qg3 + ((size_t)bh*64 + it)*1536 + hi*256 + li*8;
    const short8 qf0 = *(const short8*)(qB);
    const short8 qf1 = *(const short8*)(qB + 512);
    const short8 qf2 = *(const short8*)(qB + 1024);

    f32x16 accO0 = {}, accO1 = {};
    float rsum = 0.0f;

    const short* kBp = kg3 + ((size_t)bh*64 + w)*1536 + hi*256 + li*8;
    const short* vBp = vg3 + ((size_t)bh*64 + w)*1536 + li*8;
    const short* dBp = dist8 + (((size_t)bi*512 + (size_t)w*8 + hi)*SEQ + i0 + li)*4;

    for (int s = 0; s < 16; ++s) {
        short8 kf0 = *(const short8*)(kBp);
        short8 kf1 = *(const short8*)(kBp + 512);
        short8 kf2 = *(const short8*)(kBp + 1024);
        int2 du0 = *(const int2*)(dBp);
        int2 du1 = *(const int2*)(dBp + SEQ*8);
        int2 du2 = *(const int2*)(dBp + SEQ*16);
        int2 du3 = *(const int2*)(dBp + SEQ*24);
        f32x16 sacc = {};
        __builtin_amdgcn_s_setprio(1);
        sacc = __builtin_amdgcn_mfma_f32_32x32x16_bf16(kf0, qf0, sacc, 0, 0, 0);
        sacc = __builtin_amdgcn_mfma_f32_32x32x16_bf16(kf1, qf1, sacc, 0, 0, 0);
        sacc = __builtin_amdgcn_mfma_f32_32x32x16_bf16(kf2, qf2, sacc, 0, 0, 0);
        __builtin_amdgcn_s_setprio(0);
        float p[16];
        #pragma unroll
        for (int rq = 0; rq < 4; ++rq) {
            int2 du = rq == 0 ? du0 : rq == 1 ? du1 : rq == 2 ? du2 : du3;
            float d0 = bflo((unsigned)du.x), d1 = bfhi((unsigned)du.x);
            float d2 = bflo((unsigned)du.y), d3 = bfhi((unsigned)du.y);
            p[4*rq+0] = __builtin_amdgcn_exp2f(fmaf(sacc[4*rq+0], scale2, fmaf(d0, wd, bd)));
            p[4*rq+1] = __builtin_amdgcn_exp2f(fmaf(sacc[4*rq+1], scale2, fmaf(d1, wd, bd)));
            p[4*rq+2] = __builtin_amdgcn_exp2f(fmaf(sacc[4*rq+2], scale2, fmaf(d2, wd, bd)));
            p[4*rq+3] = __builtin_amdgcn_exp2f(fmaf(sacc[4*rq+3], scale2, fmaf(d3, wd, bd)));
            rsum += (p[4*rq+0] + p[4*rq+1]) + (p[4*rq+2] + p[4*rq+3]);
        }
        short8 pa0 = u4pack(pk2(p[0],p[1]),  pk2(p[2],p[3]),  pk2(p[4],p[5]),   pk2(p[6],p[7]));
        short8 pa1 = u4pack(pk2(p[8],p[9]),  pk2(p[10],p[11]),pk2(p[12],p[13]), pk2(p[14],p[15]));
        short8 v00 = *(const short8*)(vBp + hi*256);            // jc0, d 0..31
        short8 v10 = *(const short8*)(vBp + 768 + hi*256);      // jc1, d 0..31
        short8 v01 = *(const short8*)(vBp + 512 + hi*128);      // jc0, d 32..47 (cols>=16 junk)
        short8 v11 = *(const short8*)(vBp + 1280 + hi*128);     // jc1, d 32..47
        __builtin_amdgcn_s_setprio(1);
        accO0 = __builtin_amdgcn_mfma_f32_32x32x16_bf16(pa0, v00, accO0, 0, 0, 0);
        accO0 = __builtin_amdgcn_mfma_f32_32x32x16_bf16(pa1, v10, accO0, 0, 0, 0);
        accO1 = __builtin_amdgcn_mfma_f32_32x32x16_bf16(pa0, v01, accO1, 0, 0, 0);
        accO1 = __builtin_amdgcn_mfma_f32_32x32x16_bf16(pa1, v11, accO1, 0, 0, 0);
        __builtin_amdgcn_s_setprio(0);
        kBp += 4*1536; vBp += 4*1536; dBp += (size_t)SEQ*128;
    }
    rsum += __shfl_xor(rsum, 32);   // partner half-lane holds the other 16 j per tile

    // cross-wave tree reduction
    if (w >= 2) {
        float* Od = Ored[w-2];
        #pragma unroll
        for (int r = 0; r < 16; ++r) {
            int ii = (r & 3) + 8*(r >> 2) + 4*hi;
            Od[ii*48 + li] = accO0[r];
            if (li < 16) Od[ii*48 + 32 + li] = accO1[r];
        }
        if (lane < 32) Lred[w-2][lane] = rsum;
    }
    __syncthreads();
    if (w < 2) {
        const float* Od = Ored[w];
        #pragma unroll
        for (int r = 0; r < 16; ++r) {
            int ii = (r & 3) + 8*(r >> 2) + 4*hi;
            accO0[r] += Od[ii*48 + li];
            accO1[r] += Od[ii*48 + 32 + (li & 15)];
        }
        rsum += Lred[w][li];
    }
    __syncthreads();
    if (w == 1) {
        float* Od = Ored[0];
        #pragma unroll
        for (int r = 0; r < 16; ++r) {
            int ii = (r & 3) + 8*(r >> 2) + 4*hi;
            Od[ii*48 + li] = accO0[r];
            if (li < 16) Od[ii*48 + 32 + li] = accO1[r];
        }
        if (lane < 32) Lred[0][lane] = rsum;
    }
    __syncthreads();
    if (w == 0) {
        float* Od = Ored[0];
        #pragma unroll
        for (int r = 0; r < 16; ++r) {
            int ii = (r & 3) + 8*(r >> 2) + 4*hi;
            Od[ii*48 + li] += accO0[r];
            if (li < 16) Od[ii*48 + 32 + li] += accO1[r];
        }
        if (lane < 32) Lred[0][lane] += rsum;
    }
    __syncthreads();
    // all waves: normalize + coalesced int4 store of the 32x48 tile
    for (int c = t; c < 192; c += 256) {
        int r = c / 6, d8 = (c % 6)*8;
        float inv = 1.0f / Lred[0][r];
        const float* src = &Ored[0][r*48 + d8];
        short o[8];
        #pragma unroll
        for (int e = 0; e < 8; ++e) o[e] = f2b(src[e]*inv);
        *(int4*)(aob + ((size_t)(bi*SEQ) + i0 + r)*DM + hh*HD + d8) = *(const int4*)o;
    }
}

// ---------------- K4: MFMA GEMM out = aob @ Wout + b_out
__global__ __launch_bounds__(256) void k_out(const short* __restrict__ aob,
    const short* __restrict__ WT, const float* __restrict__ bias,
    void* __restrict__ out, const void* __restrict__ x)
{
    __shared__ __align__(16) short As[64*72];
    __shared__ __align__(16) short Bs[128*72];
    const int isf = detect_isf(x);
    const int t = threadIdx.x;
    const int w = t >> 6, lane = t & 63, L = lane & 15, quad = lane >> 4;
    const int mt = blockIdx.x / 3, nt = blockIdx.x % 3;
    const int row0 = mt*64, col0 = nt*128;
    const int wm = w & 1, wn = w >> 1;
    float4v acc[2][4] = {};
    for (int k0 = 0; k0 < DM; k0 += 64) {
        __syncthreads();
        for (int c = t; c < 512; c += 256) {
            int row = c >> 3, k8 = c & 7;
            *(int4*)(&As[row*72 + k8*8]) = *(const int4*)(aob + (size_t)(row0+row)*DM + k0 + k8*8);
        }
        for (int c = t; c < 1024; c += 256) {
            int row = c >> 3, k8 = c & 7;
            *(int4*)(&Bs[row*72 + k8*8]) = *(const int4*)(WT + (size_t)(col0+row)*DM + k0 + k8*8);
        }
        __syncthreads();
        #pragma unroll
        for (int kc = 0; kc < 2; ++kc) {
            short8 a0 = *(const short8*)(&As[(32*wm + L)*72 + kc*32 + quad*8]);
            short8 a1 = *(const short8*)(&As[(32*wm + 16 + L)*72 + kc*32 + quad*8]);
            #pragma unroll
            for (int ni = 0; ni < 4; ++ni) {
                short8 bf = *(const short8*)(&Bs[(64*wn + 16*ni + L)*72 + kc*32 + quad*8]);
                acc[0][ni] = __builtin_amdgcn_mfma_f32_16x16x32_bf16(a0, bf, acc[0][ni], 0, 0, 0);
                acc[1][ni] = __builtin_amdgcn_mfma_f32_16x16x32_bf16(a1, bf, acc[1][ni], 0, 0, 0);
            }
        }
    }
    #pragma unroll
    for (int mi = 0; mi < 2; ++mi) {
        #pragma unroll
        for (int ni = 0; ni < 4; ++ni) {
            int col_g = col0 + 64*wn + 16*ni + L;
            float bv = bias[col_g];
            #pragma unroll
            for (int r = 0; r < 4; ++r) {
                int row_g = row0 + 32*wm + 16*mi + quad*4 + r;
                size_t oi = (size_t)row_g*DM + col_g;
                float val = acc[mi][ni][r] + bv;
                if (isf) ((float*)out)[oi] = val;
                else     ((bf16*)out)[oi]  = __float2bfloat16(val);
            }
        }
    }
}

extern "C" void kernel_launch(void* const* d_in, const int* in_sizes, int n_in,
                              void* d_out, int out_size, void* d_ws, size_t ws_size,
                              hipStream_t stream) {
    const void* x      = d_in[0];
    const void* coords = d_in[1];
    const void* Wqkv   = d_in[2];
    const void* bqkv   = d_in[3];
    const void* Wdist  = d_in[4];
    const void* bdist  = d_in[5];
    const void* Wout   = d_in[6];
    const void* bout   = d_in[7];

    short* qg3   = (short*)d_ws;                       // 16*64*1536 = 1,572,864
    short* kg3   = qg3  + (size_t)1572864;
    short* vg3   = kg3  + (size_t)1572864;             // + 256 overread pad
    short* dist8 = vg3  + (size_t)1573120;             // 2*512*2048*4 = 8,388,608
    short* aob   = dist8 + (size_t)8388608;
    short* WqT   = aob  + (size_t)1572864;
    short* WoT   = WqT  + (size_t)442368;
    float* bqf   = (float*)(WoT + (size_t)147456);     // 16B-aligned
    float* bof   = bqf + QKVN;
    float* wdf   = bof + DM;
    float* bdf   = wdf + NH;

    k_wt<<<dim3(583), dim3(256), 0, stream>>>(x, Wqkv, Wout, bqkv, bout, Wdist, bdist,
                                              WqT, WoT, bqf, bof, wdf, bdf);
    k_qkv_dist<<<dim3(1088), dim3(256), 0, stream>>>(x, coords, WqT, bqf,
                                                     qg3, kg3, vg3, dist8);
    k_attn<<<dim3(1024), dim3(256), 0, stream>>>(qg3, kg3, vg3, dist8, wdf, bdf, aob);
    k_out<<<dim3(192), dim3(256), 0, stream>>>(aob, WoT, bof, d_out, x);
}